// Round 7
// baseline (197.599 us; speedup 1.0000x reference)
//
#include <hip/hip_runtime.h>
#include <hip/hip_bf16.h>

// ---------------- constants ----------------
__device__ __constant__ int GRADE_C[16] = {0,1,1,1,1,2,2,2,2,2,2,3,3,3,3,4};
__device__ __constant__ int INNER_C[8]  = {0,2,3,4,8,9,10,14};

// workspace layout (bytes unless noted)
#define OFF_GH    0         // float idx 0..15: Gh[8], Ch[8]
#define GWBT_BYTE 4096      // gwBT[j(16)][c(128)] bf16, k-slot PERMUTED : 4 KB
#define KFB_BYTE  16384     // kf[n][64] bf16                            : 128 KB
#define VTB_BYTE  262144    // Vt[comp(96)][n(1024)] bf16                : 192 KB
#define QFB_BYTE  524288    // qfb[q][j(16)][d(64)] bf16                 : 2 MB

typedef __attribute__((ext_vector_type(8))) short bf16x8;
typedef __attribute__((ext_vector_type(4))) float f32x4;
typedef __attribute__((ext_vector_type(4))) unsigned int u32x4;

static __device__ __forceinline__ unsigned short f2bf(float f) {
    unsigned int u = __float_as_uint(f);
    u = u + 0x7fffu + ((u >> 16) & 1u);
    return (unsigned short)(u >> 16);
}
static __device__ __forceinline__ unsigned pk2(float lo, float hi) {
    return (unsigned)f2bf(lo) | ((unsigned)f2bf(hi) << 16);
}
static __device__ __forceinline__ unsigned cvtpk(float lo, float hi) {
    __hip_bfloat162 c = __float22bfloat162_rn(make_float2(lo, hi));
    unsigned u;
    __builtin_memcpy(&u, &c, 4);
    return u;
}
static __device__ __forceinline__ float bflo(unsigned int u) {
    return __uint_as_float(u << 16);
}
static __device__ __forceinline__ float bfhi(unsigned int u) {
    return __uint_as_float(u & 0xffff0000u);
}

// async global->LDS, 16B per lane. LDS dest = wave-uniform base + lane*16.
static __device__ __forceinline__ void gload16(const void* g, void* l) {
    __builtin_amdgcn_global_load_lds(
        (const __attribute__((address_space(1))) unsigned int*)g,
        (__attribute__((address_space(3))) unsigned int*)l, 16, 0, 0);
}

// ---------------- kernel P: projections (unchanged, validated) ----------------
__global__ __launch_bounds__(256) void kproj(
    const float* __restrict__ mv, const float* __restrict__ s,
    const float* __restrict__ q_w_mv, const float* __restrict__ q_w_s,
    const float* __restrict__ k_w_mv, const float* __restrict__ k_w_s,
    const float* __restrict__ v_w_mv, const float* __restrict__ v_w_s,
    const float* __restrict__ ln_g, const float* __restrict__ ln_b,
    const float* __restrict__ bias_w, float* __restrict__ ws)
{
    __shared__ __align__(16) float mvn[256];
    __shared__ __align__(16) float sn[128];
    __shared__ float qs_pre[256];
    __shared__ float ks_pre[32];
    __shared__ float vs_pre[32];
    const int n = blockIdx.x, t = threadIdx.x;

    unsigned short* kfb = (unsigned short*)((char*)ws + KFB_BYTE);
    unsigned short* qfb = (unsigned short*)((char*)ws + QFB_BYTE);
    unsigned short* gwp = (unsigned short*)((char*)ws + GWBT_BYTE);
    unsigned short* vtb = (unsigned short*)((char*)ws + VTB_BYTE);

    mvn[t] = mv[n * 256 + t];
    if (t < 128) sn[t] = s[n * 128 + t];
    __syncthreads();

    {
        const float4* w = (const float4*)(q_w_s + t * 128);
        const float4* sv = (const float4*)sn;
        float acc = 0.f;
        #pragma unroll
        for (int c4 = 0; c4 < 32; ++c4) {
            float4 wv = w[c4], x = sv[c4];
            acc += wv.x * x.x + wv.y * x.y + wv.z * x.z + wv.w * x.w;
        }
        qs_pre[t] = acc;
    }
    if (t < 64) {
        const float* wb = (t < 32) ? (k_w_s + t * 128) : (v_w_s + (t - 32) * 128);
        const float4* w = (const float4*)wb;
        const float4* sv = (const float4*)sn;
        float acc = 0.f;
        #pragma unroll
        for (int c4 = 0; c4 < 32; ++c4) {
            float4 wv = w[c4], x = sv[c4];
            acc += wv.x * x.x + wv.y * x.y + wv.z * x.z + wv.w * x.w;
        }
        if (t < 32) ks_pre[t] = acc; else vs_pre[t - 32] = acc;
    }
    {
        int o = t >> 3, j = t & 7;
        int bx = INNER_C[j], g = GRADE_C[bx];
        float acc = 0.f;
        #pragma unroll
        for (int i = 0; i < 16; ++i)
            acc += mvn[i * 16 + bx] * q_w_mv[(o * 16 + i) * 5 + g];
        int h = o >> 2, c = o & 3, d = c * 8 + j;
        qfb[n * 1024 + h * 64 + d] = f2bf(acc);
    }
    {
        int hp = 8 + (t >> 5), d = t & 31;
        qfb[n * 1024 + hp * 64 + d] = 0;
        qfb[n * 1024 + hp * 64 + 32 + d] = 0;
    }
    if (t < 32) {
        int bx = INNER_C[t & 7], g = GRADE_C[bx];
        float acc = 0.f;
        #pragma unroll
        for (int i = 0; i < 16; ++i)
            acc += mvn[i * 16 + bx] * k_w_mv[((t >> 3) * 16 + i) * 5 + g];
        kfb[n * 64 + t] = f2bf(acc);
    }
    if (t >= 64 && t < 128) {
        int idx = t - 64, x = idx & 15, g = GRADE_C[x];
        float acc = 0.f;
        #pragma unroll
        for (int i = 0; i < 16; ++i)
            acc += mvn[i * 16 + x] * v_w_mv[((idx >> 4) * 16 + i) * 5 + g];
        vtb[idx * 1024 + n] = f2bf(acc);
    }
    __syncthreads();

    {
        int h = t >> 5, dd = t & 31, i = dd >> 1;
        float freq = exp2f(-0.75f * (float)i);
        float ang = (float)n * freq;
        float cv = cosf(ang), sv = sinf(ang);
        float x1 = qs_pre[h * 32 + 2 * i], x2 = qs_pre[h * 32 + 2 * i + 1];
        float val = ((dd & 1) == 0) ? (x1 * cv - x2 * sv) : (x1 * sv + x2 * cv);
        qfb[n * 1024 + h * 64 + 32 + dd] = f2bf(val);
    }
    if (t < 32) {
        int i = t >> 1;
        float freq = exp2f(-0.75f * (float)i);
        float ang = (float)n * freq;
        float cv = cosf(ang), sv = sinf(ang);
        float x1 = ks_pre[2 * i], x2 = ks_pre[2 * i + 1];
        float val = ((t & 1) == 0) ? (x1 * cv - x2 * sv) : (x1 * sv + x2 * cv);
        kfb[n * 64 + 32 + t] = f2bf(val);
    }
    if (t >= 32 && t < 64) vtb[(64 + t - 32) * 1024 + n] = f2bf(vs_pre[t - 32]);

    if (n == 0) {
        if (t < 128) {
            int cb = t >> 5, r = t & 31;
            int lg, e;
            if (r < 16) { lg = r >> 2; e = r & 3; }
            else        { lg = (r - 16) >> 2; e = 4 + (r & 3); }
            int pos = cb * 32 + lg * 8 + e;
            float g = ln_g[t];
            #pragma unroll
            for (int j = 0; j < 8; ++j)
                gwp[j * 128 + pos] = f2bf(g * bias_w[t * 8 + j]);
            gwp[8 * 128 + pos] = 0x3F80;
            #pragma unroll
            for (int j = 9; j < 16; ++j) gwp[j * 128 + pos] = 0;
        }
        if (t >= 128 && t < 136) {
            int h = t - 128;
            float gh = 0.f, ch = 0.f;
            for (int c = 0; c < 128; ++c) {
                gh += ln_g[c] * bias_w[c * 8 + h];
                ch += ln_b[c] * bias_w[c * 8 + h];
            }
            ws[OFF_GH + h] = gh;
            ws[OFF_GH + 8 + h] = ch;
        }
    }
}

// ---------------- kernel F: gload_lds-staged fused kernel ----------------
// 8 waves, 1 block per q. Phase = 128 k-rows (64 KB), LDS double-buffered,
// counted vmcnt (never 0 mid-loop). LN finalize fully in-register.
__global__ __launch_bounds__(512) void kfused(
    const float* __restrict__ z, const float* __restrict__ ws,
    const float* __restrict__ out_w_mv, const float* __restrict__ out_w_s,
    float* __restrict__ d_out)
{
    __shared__ __align__(16) char lds[147456];       // 128 KB z dbuf + 16 KB Pb
    unsigned int* Pb = (unsigned int*)(lds + 131072); // bf16 s/P [h(8)][k(1024)], swizzled
    float* o_sh  = (float*)lds;                       // aliases z buf (post-loop)
    float* inv_l = (float*)(lds + 3072);

    const int q = blockIdx.x, t = threadIdx.x;
    const int w = t >> 6, l = t & 63, lm = l & 15, lg = l >> 4;

    // persistent fragments (loaded once)
    bf16x8 B1[4], B2[2], A2[8][2];
    #pragma unroll
    for (int ks = 0; ks < 4; ++ks)
        B1[ks] = *(const bf16x8*)((const char*)ws + GWBT_BYTE + (lm * 128 + ks * 32 + lg * 8) * 2);
    #pragma unroll
    for (int ds = 0; ds < 2; ++ds)
        B2[ds] = *(const bf16x8*)((const char*)ws + QFB_BYTE + ((size_t)q * 1024 + lm * 64 + ds * 32 + lg * 8) * 2);
    {
        const unsigned short* kfb = (const unsigned short*)((const char*)ws + KFB_BYTE);
        #pragma unroll
        for (int p = 0; p < 8; ++p) {
            int krow = p * 128 + w * 16 + lm;
            A2[p][0] = *(const bf16x8*)(kfb + (size_t)krow * 64 + lg * 8);
            A2[p][1] = *(const bf16x8*)(kfb + (size_t)krow * 64 + 32 + lg * 8);
        }
    }
    const float Gh_l = ws[OFF_GH + (lm & 7)];
    const float Ch_l = ws[OFF_GH + 8 + (lm & 7)];

    const char* zq = (const char*)z + (size_t)q * 1024 * 512;
    const int srow = l >> 5, schunk = l & 31;

    // stage phase p (128 rows, 64 KB) into buffer b; source chunk-swizzled so
    // linear LDS holds swizzled layout; wave's 1KB per instr is a contiguous SET.
#define STAGE(p, b) do {                                                        \
    const char* zp_ = zq + ((size_t)(p) * 128 + w * 16) * 512;                  \
    char* lb_ = lds + (b) * 65536 + w * 8192;                                   \
    _Pragma("unroll")                                                           \
    for (int i_ = 0; i_ < 8; ++i_) {                                            \
        int R_ = i_ * 2 + srow;                                                 \
        gload16(zp_ + (size_t)R_ * 512 + ((schunk ^ R_) << 4), lb_ + i_ * 1024);\
    }                                                                           \
} while (0)

    asm volatile("s_waitcnt vmcnt(0)" ::: "memory");   // drain init loads: exact counting
    STAGE(0, 0);
    STAGE(1, 1);

    #pragma unroll
    for (int p = 0; p < 8; ++p) {
        if (p < 7) { asm volatile("s_waitcnt vmcnt(8)" ::: "memory"); }
        else       { asm volatile("s_waitcnt vmcnt(0)" ::: "memory"); }
        __builtin_amdgcn_sched_barrier(0);
        __builtin_amdgcn_s_barrier();

        // fragments from LDS (swizzled read matches swizzled source)
        const char* zt = lds + (p & 1) * 65536 + (w * 16 + lm) * 512;
        float4 za[4], zb4[4];
        #pragma unroll
        for (int ks = 0; ks < 4; ++ks) {
            za[ks]  = *(const float4*)(zt + (((lg + ks * 8)     ^ lm) << 4));
            zb4[ks] = *(const float4*)(zt + (((lg + ks * 8 + 4) ^ lm) << 4));
        }

        f32x4 acc1 = {0.f, 0.f, 0.f, 0.f};
        f32x4 acc2 = {0.f, 0.f, 0.f, 0.f};
        float sq = 0.f;
        #pragma unroll
        for (int ks = 0; ks < 4; ++ks) {
            float4 A = za[ks], Bv = zb4[ks];
            sq = __builtin_fmaf(A.x, A.x, sq);   sq = __builtin_fmaf(A.y, A.y, sq);
            sq = __builtin_fmaf(A.z, A.z, sq);   sq = __builtin_fmaf(A.w, A.w, sq);
            sq = __builtin_fmaf(Bv.x, Bv.x, sq); sq = __builtin_fmaf(Bv.y, Bv.y, sq);
            sq = __builtin_fmaf(Bv.z, Bv.z, sq); sq = __builtin_fmaf(Bv.w, Bv.w, sq);
            u32x4 au;
            au[0] = cvtpk(A.x, A.y);   au[1] = cvtpk(A.z, A.w);
            au[2] = cvtpk(Bv.x, Bv.y); au[3] = cvtpk(Bv.z, Bv.w);
            bf16x8 af = __builtin_bit_cast(bf16x8, au);
            acc1 = __builtin_amdgcn_mfma_f32_16x16x32_bf16(af, B1[ks], acc1, 0, 0, 0);
        }
        acc2 = __builtin_amdgcn_mfma_f32_16x16x32_bf16(A2[p][0], B2[0], acc2, 0, 0, 0);
        acc2 = __builtin_amdgcn_mfma_f32_16x16x32_bf16(A2[p][1], B2[1], acc2, 0, 0, 0);

        // full-row sumsq broadcast to all lanes (row = w*16+lm)
        sq += __shfl_xor(sq, 16);
        sq += __shfl_xor(sq, 32);

        // in-register finalize: acc1[r]/acc2[r] live at D[row lg*4+r][col lm]
        float sval[4];
        #pragma unroll
        for (int r = 0; r < 4; ++r) {
            float ssq_r = __shfl(sq, lg * 4 + r);            // ssq of row lg*4+r
            float sum_r = __shfl(acc1[r], lg * 16 + 8);      // ones-column = row sum
            float mean = sum_r * (1.f / 128.f);
            float var  = ssq_r * (1.f / 128.f) - mean * mean;
            float rs   = rsqrtf(var + 1e-5f);
            float bias = rs * (acc1[r] - mean * Gh_l) + Ch_l;
            sval[r] = acc2[r] * 0.125f + bias;
        }
        if (lm < 8) {
            int wp = p * 64 + w * 8 + lg * 2;
            Pb[lm * 512 + ( wp      ^ (lm << 2))] = cvtpk(sval[0], sval[1]);
            Pb[lm * 512 + ((wp + 1) ^ (lm << 2))] = cvtpk(sval[2], sval[3]);
        }

        __builtin_amdgcn_s_barrier();     // all waves done reading buf[p&1]
        if (p < 6) STAGE(p + 2, p & 1);
    }
    __syncthreads();

    // ---- softmax per head, in place on bf16 Pb (one wave per head) ----
    {
        const int h = t >> 6, e = t & 63, hx = h << 2;
        unsigned int* Ph = &Pb[h * 512];
        float m = -1e30f;
        #pragma unroll
        for (int j = 0; j < 8; ++j) {
            unsigned int v = Ph[(e + j * 64) ^ hx];
            m = fmaxf(m, fmaxf(bflo(v), bfhi(v)));
        }
        #pragma unroll
        for (int d = 32; d >= 1; d >>= 1) m = fmaxf(m, __shfl_xor(m, d));
        float lsum = 0.f;
        #pragma unroll
        for (int j = 0; j < 8; ++j) {
            int idx = (e + j * 64) ^ hx;
            unsigned int v = Ph[idx];
            float p0 = __expf(bflo(v) - m);
            float p1 = __expf(bfhi(v) - m);
            lsum += p0 + p1;
            Ph[idx] = pk2(p0, p1);
        }
        #pragma unroll
        for (int d = 32; d >= 1; d >>= 1) lsum += __shfl_xor(lsum, d);
        if (e == 0) inv_l[h] = 1.f / lsum;
    }
    __syncthreads();

    // ---- PV via MFMA: C[comp][head] = Vt(96x1024) . P^T(1024x16) ----
    {
        const unsigned short* vtb = (const unsigned short*)((const char*)ws + VTB_BYTE);
        const char* PbB = (const char*)Pb;
        const int hh = lm & 7;
        if (w < 6) {
            int mt = w;
            f32x4 acc = {0.f, 0.f, 0.f, 0.f};
            #pragma unroll 8
            for (int ks = 0; ks < 32; ++ks) {
                bf16x8 a = *(const bf16x8*)(vtb + (size_t)(mt * 16 + lm) * 1024 + ks * 32 + lg * 8);
                bf16x8 b = *(const bf16x8*)(PbB + hh * 2048 + ((ks * 64 + lg * 16) ^ (hh << 4)));
                acc = __builtin_amdgcn_mfma_f32_16x16x32_bf16(a, b, acc, 0, 0, 0);
            }
            if (lm < 8) {
                float il = inv_l[lm];
                #pragma unroll
                for (int r = 0; r < 4; ++r)
                    o_sh[lm * 96 + mt * 16 + lg * 4 + r] = acc[r] * il;
            }
        }
    }
    __syncthreads();

    // ---- output projections ----
    if (t < 256) {
        int o2 = t >> 4, b = t & 15, g = GRADE_C[b];
        float acc = 0.f;
        #pragma unroll
        for (int i = 0; i < 32; ++i)
            acc += o_sh[(i >> 2) * 96 + (i & 3) * 16 + b] *
                   out_w_mv[(o2 * 32 + i) * 5 + g];
        d_out[(q * 16 + o2) * 16 + b] = acc;
    }
    if (t >= 256 && t < 384) {
        int tt = t - 256;
        const float* wv2 = out_w_s + tt * 256;
        float acc = 0.f;
        #pragma unroll 4
        for (int c = 0; c < 256; ++c)
            acc += o_sh[(c >> 5) * 96 + 64 + (c & 31)] * wv2[c];
        d_out[262144 + q * 128 + tt] = acc;
    }
#undef STAGE
}

// ---------------- launch ----------------
extern "C" void kernel_launch(void* const* d_in, const int* in_sizes, int n_in,
                              void* d_out, int out_size, void* d_ws, size_t ws_size,
                              hipStream_t stream) {
    (void)in_sizes; (void)n_in; (void)out_size; (void)ws_size;
    const float* mv       = (const float*)d_in[0];
    const float* s        = (const float*)d_in[1];
    const float* z        = (const float*)d_in[2];
    const float* q_w_mv   = (const float*)d_in[3];
    const float* q_w_s    = (const float*)d_in[4];
    const float* k_w_mv   = (const float*)d_in[5];
    const float* k_w_s    = (const float*)d_in[6];
    const float* v_w_mv   = (const float*)d_in[7];
    const float* v_w_s    = (const float*)d_in[8];
    const float* out_w_mv = (const float*)d_in[9];
    const float* out_w_s  = (const float*)d_in[10];
    const float* ln_g     = (const float*)d_in[11];
    const float* ln_b     = (const float*)d_in[12];
    const float* bias_w   = (const float*)d_in[13];
    float* ws  = (float*)d_ws;
    float* out = (float*)d_out;

    kproj<<<1024, 256, 0, stream>>>(mv, s, q_w_mv, q_w_s, k_w_mv, k_w_s,
                                    v_w_mv, v_w_s, ln_g, ln_b, bias_w, ws);
    kfused<<<1024, 512, 0, stream>>>(z, ws, out_w_mv, out_w_s, out);
}

// Round 8
// 174.363 us; speedup vs baseline: 1.1333x; 1.1333x over previous
//
#include <hip/hip_runtime.h>
#include <hip/hip_bf16.h>

// ---------------- constants ----------------
__device__ __constant__ int GRADE_C[16] = {0,1,1,1,1,2,2,2,2,2,2,3,3,3,3,4};
__device__ __constant__ int INNER_C[8]  = {0,2,3,4,8,9,10,14};

// workspace layout (bytes unless noted)
#define OFF_GH    0         // float idx 0..15: Gh[8], Ch[8]
#define GWBT_BYTE 4096      // gwBT[j(16)][c(128)] bf16, k-slot PERMUTED : 4 KB
#define KFB_BYTE  16384     // kf[n][64] bf16                            : 128 KB
#define VTB_BYTE  262144    // Vt[comp(96)][n(1024)] bf16                : 192 KB
#define QFB_BYTE  524288    // qfb[q][j(16)][d(64)] bf16                 : 2 MB

typedef __attribute__((ext_vector_type(8))) short bf16x8;
typedef __attribute__((ext_vector_type(4))) float f32x4;
typedef __attribute__((ext_vector_type(4))) unsigned int u32x4;

static __device__ __forceinline__ unsigned short f2bf(float f) {
    unsigned int u = __float_as_uint(f);
    u = u + 0x7fffu + ((u >> 16) & 1u);
    return (unsigned short)(u >> 16);
}
static __device__ __forceinline__ unsigned pk2(float lo, float hi) {
    return (unsigned)f2bf(lo) | ((unsigned)f2bf(hi) << 16);
}
static __device__ __forceinline__ unsigned cvtpk(float lo, float hi) {
    __hip_bfloat162 c = __float22bfloat162_rn(make_float2(lo, hi));
    unsigned u;
    __builtin_memcpy(&u, &c, 4);
    return u;
}
static __device__ __forceinline__ float bflo(unsigned int u) {
    return __uint_as_float(u << 16);
}
static __device__ __forceinline__ float bfhi(unsigned int u) {
    return __uint_as_float(u & 0xffff0000u);
}

// ---------------- kernel P: projections (unchanged, validated) ----------------
__global__ __launch_bounds__(256) void kproj(
    const float* __restrict__ mv, const float* __restrict__ s,
    const float* __restrict__ q_w_mv, const float* __restrict__ q_w_s,
    const float* __restrict__ k_w_mv, const float* __restrict__ k_w_s,
    const float* __restrict__ v_w_mv, const float* __restrict__ v_w_s,
    const float* __restrict__ ln_g, const float* __restrict__ ln_b,
    const float* __restrict__ bias_w, float* __restrict__ ws)
{
    __shared__ __align__(16) float mvn[256];
    __shared__ __align__(16) float sn[128];
    __shared__ float qs_pre[256];
    __shared__ float ks_pre[32];
    __shared__ float vs_pre[32];
    const int n = blockIdx.x, t = threadIdx.x;

    unsigned short* kfb = (unsigned short*)((char*)ws + KFB_BYTE);
    unsigned short* qfb = (unsigned short*)((char*)ws + QFB_BYTE);
    unsigned short* gwp = (unsigned short*)((char*)ws + GWBT_BYTE);
    unsigned short* vtb = (unsigned short*)((char*)ws + VTB_BYTE);

    mvn[t] = mv[n * 256 + t];
    if (t < 128) sn[t] = s[n * 128 + t];
    __syncthreads();

    {
        const float4* w = (const float4*)(q_w_s + t * 128);
        const float4* sv = (const float4*)sn;
        float acc = 0.f;
        #pragma unroll
        for (int c4 = 0; c4 < 32; ++c4) {
            float4 wv = w[c4], x = sv[c4];
            acc += wv.x * x.x + wv.y * x.y + wv.z * x.z + wv.w * x.w;
        }
        qs_pre[t] = acc;
    }
    if (t < 64) {
        const float* wb = (t < 32) ? (k_w_s + t * 128) : (v_w_s + (t - 32) * 128);
        const float4* w = (const float4*)wb;
        const float4* sv = (const float4*)sn;
        float acc = 0.f;
        #pragma unroll
        for (int c4 = 0; c4 < 32; ++c4) {
            float4 wv = w[c4], x = sv[c4];
            acc += wv.x * x.x + wv.y * x.y + wv.z * x.z + wv.w * x.w;
        }
        if (t < 32) ks_pre[t] = acc; else vs_pre[t - 32] = acc;
    }
    {
        int o = t >> 3, j = t & 7;
        int bx = INNER_C[j], g = GRADE_C[bx];
        float acc = 0.f;
        #pragma unroll
        for (int i = 0; i < 16; ++i)
            acc += mvn[i * 16 + bx] * q_w_mv[(o * 16 + i) * 5 + g];
        int h = o >> 2, c = o & 3, d = c * 8 + j;
        qfb[n * 1024 + h * 64 + d] = f2bf(acc);
    }
    {
        int hp = 8 + (t >> 5), d = t & 31;
        qfb[n * 1024 + hp * 64 + d] = 0;
        qfb[n * 1024 + hp * 64 + 32 + d] = 0;
    }
    if (t < 32) {
        int bx = INNER_C[t & 7], g = GRADE_C[bx];
        float acc = 0.f;
        #pragma unroll
        for (int i = 0; i < 16; ++i)
            acc += mvn[i * 16 + bx] * k_w_mv[((t >> 3) * 16 + i) * 5 + g];
        kfb[n * 64 + t] = f2bf(acc);
    }
    if (t >= 64 && t < 128) {
        int idx = t - 64, x = idx & 15, g = GRADE_C[x];
        float acc = 0.f;
        #pragma unroll
        for (int i = 0; i < 16; ++i)
            acc += mvn[i * 16 + x] * v_w_mv[((idx >> 4) * 16 + i) * 5 + g];
        vtb[idx * 1024 + n] = f2bf(acc);
    }
    __syncthreads();

    {
        int h = t >> 5, dd = t & 31, i = dd >> 1;
        float freq = exp2f(-0.75f * (float)i);
        float ang = (float)n * freq;
        float cv = cosf(ang), sv = sinf(ang);
        float x1 = qs_pre[h * 32 + 2 * i], x2 = qs_pre[h * 32 + 2 * i + 1];
        float val = ((dd & 1) == 0) ? (x1 * cv - x2 * sv) : (x1 * sv + x2 * cv);
        qfb[n * 1024 + h * 64 + 32 + dd] = f2bf(val);
    }
    if (t < 32) {
        int i = t >> 1;
        float freq = exp2f(-0.75f * (float)i);
        float ang = (float)n * freq;
        float cv = cosf(ang), sv = sinf(ang);
        float x1 = ks_pre[2 * i], x2 = ks_pre[2 * i + 1];
        float val = ((t & 1) == 0) ? (x1 * cv - x2 * sv) : (x1 * sv + x2 * cv);
        kfb[n * 64 + 32 + t] = f2bf(val);
    }
    if (t >= 32 && t < 64) vtb[(64 + t - 32) * 1024 + n] = f2bf(vs_pre[t - 32]);

    if (n == 0) {
        if (t < 128) {
            int cb = t >> 5, r = t & 31;
            int lg, e;
            if (r < 16) { lg = r >> 2; e = r & 3; }
            else        { lg = (r - 16) >> 2; e = 4 + (r & 3); }
            int pos = cb * 32 + lg * 8 + e;
            float g = ln_g[t];
            #pragma unroll
            for (int j = 0; j < 8; ++j)
                gwp[j * 128 + pos] = f2bf(g * bias_w[t * 8 + j]);
            gwp[8 * 128 + pos] = 0x3F80;
            #pragma unroll
            for (int j = 9; j < 16; ++j) gwp[j * 128 + pos] = 0;
        }
        if (t >= 128 && t < 136) {
            int h = t - 128;
            float gh = 0.f, ch = 0.f;
            for (int c = 0; c < 128; ++c) {
                gh += ln_g[c] * bias_w[c * 8 + h];
                ch += ln_b[c] * bias_w[c * 8 + h];
            }
            ws[OFF_GH + h] = gh;
            ws[OFF_GH + 8 + h] = ch;
        }
    }
}

// ---------------- kernel F: barrier-free streaming fused kernel ----------------
// One block per q, 4 waves. 16 phases of 64 k-rows; each wave owns 16 rows/phase.
// Register double-buffer (zA/zB) gives one-full-phase load lookahead. LN+bias
// finalize fully in-register (shuffles on MFMA C-layout) -> NO barrier in loop.
__global__ __launch_bounds__(256, 3) void kfused(
    const float* __restrict__ z, const float* __restrict__ ws,
    const float* __restrict__ out_w_mv, const float* __restrict__ out_w_s,
    float* __restrict__ d_out)
{
    __shared__ __align__(16) unsigned int Pb[8 * 512];  // bf16 s/P [h(8)][k(1024)], swizzled
    __shared__ float inv_l[8];
    __shared__ float o_sh[8 * 96];                      // [h][comp]

    const int q = blockIdx.x, t = threadIdx.x;
    const int w = t >> 6, l = t & 63, lm = l & 15, lg = l >> 4;

    // persistent B fragments
    bf16x8 B1[4], B2[2];
    #pragma unroll
    for (int ks = 0; ks < 4; ++ks)
        B1[ks] = *(const bf16x8*)((const char*)ws + GWBT_BYTE + (lm * 128 + ks * 32 + lg * 8) * 2);
    #pragma unroll
    for (int ds = 0; ds < 2; ++ds)
        B2[ds] = *(const bf16x8*)((const char*)ws + QFB_BYTE + ((size_t)q * 1024 + lm * 64 + ds * 32 + lg * 8) * 2);

    const unsigned short* kfb = (const unsigned short*)((const char*)ws + KFB_BYTE);
    const float Gh_l = ws[OFF_GH + (lm & 7)];
    const float Ch_l = ws[OFF_GH + 8 + (lm & 7)];
    const char* zq = (const char*)z + (size_t)q * 1024 * 512;

    float4 zA[8], zB[8];

    // loads 16 rows x 64B-half-lines; element at k-slot (ks,e) = channel
    // ks*32 + [0:lg*4+e | 1:16+lg*4+e]  (matches gwBT permutation)
#define LOADZ(p, Z) do {                                                        \
    const char* zr_ = zq + (size_t)((p) * 64 + w * 16 + lm) * 512 + lg * 16;    \
    Z[0] = *(const float4*)(zr_);        Z[4] = *(const float4*)(zr_ + 64);     \
    Z[1] = *(const float4*)(zr_ + 128);  Z[5] = *(const float4*)(zr_ + 192);    \
    Z[2] = *(const float4*)(zr_ + 256);  Z[6] = *(const float4*)(zr_ + 320);    \
    Z[3] = *(const float4*)(zr_ + 384);  Z[7] = *(const float4*)(zr_ + 448);    \
} while (0)

#define PHASE(p, ZC, ZN) do {                                                   \
    const int krow_ = (p) * 64 + w * 16 + lm;                                   \
    /* kf fragments issued BEFORE next-z so their wait leaves z in flight */    \
    bf16x8 A2a_ = *(const bf16x8*)(kfb + (size_t)krow_ * 64 + lg * 8);          \
    bf16x8 A2b_ = *(const bf16x8*)(kfb + (size_t)krow_ * 64 + 32 + lg * 8);     \
    if ((p) < 15) LOADZ((p) + 1, ZN);                                           \
    f32x4 acc1 = {0.f, 0.f, 0.f, 0.f};                                          \
    f32x4 acc2 = {0.f, 0.f, 0.f, 0.f};                                          \
    float sq = 0.f;                                                             \
    _Pragma("unroll")                                                           \
    for (int ks = 0; ks < 4; ++ks) {                                            \
        float4 A = ZC[ks], Bv = ZC[4 + ks];                                     \
        sq = __builtin_fmaf(A.x, A.x, sq);   sq = __builtin_fmaf(A.y, A.y, sq); \
        sq = __builtin_fmaf(A.z, A.z, sq);   sq = __builtin_fmaf(A.w, A.w, sq); \
        sq = __builtin_fmaf(Bv.x, Bv.x, sq); sq = __builtin_fmaf(Bv.y, Bv.y, sq);\
        sq = __builtin_fmaf(Bv.z, Bv.z, sq); sq = __builtin_fmaf(Bv.w, Bv.w, sq);\
        u32x4 au;                                                               \
        au[0] = cvtpk(A.x, A.y);   au[1] = cvtpk(A.z, A.w);                     \
        au[2] = cvtpk(Bv.x, Bv.y); au[3] = cvtpk(Bv.z, Bv.w);                   \
        bf16x8 af = __builtin_bit_cast(bf16x8, au);                             \
        acc1 = __builtin_amdgcn_mfma_f32_16x16x32_bf16(af, B1[ks], acc1, 0, 0, 0);\
    }                                                                           \
    acc2 = __builtin_amdgcn_mfma_f32_16x16x32_bf16(A2a_, B2[0], acc2, 0, 0, 0); \
    acc2 = __builtin_amdgcn_mfma_f32_16x16x32_bf16(A2b_, B2[1], acc2, 0, 0, 0); \
    sq += __shfl_xor(sq, 16);                                                   \
    sq += __shfl_xor(sq, 32);                                                   \
    float sval[4];                                                              \
    _Pragma("unroll")                                                           \
    for (int r = 0; r < 4; ++r) {                                               \
        float ssq_r = __shfl(sq, lg * 4 + r);                                   \
        float sum_r = __shfl(acc1[r], lg * 16 + 8);                             \
        float mean = sum_r * (1.f / 128.f);                                     \
        float var  = ssq_r * (1.f / 128.f) - mean * mean;                       \
        float rs   = rsqrtf(var + 1e-5f);                                       \
        float bias = rs * (acc1[r] - mean * Gh_l) + Ch_l;                       \
        sval[r] = acc2[r] * 0.125f + bias;                                      \
    }                                                                           \
    if (lm < 8) {                                                               \
        int wp = (p) * 32 + w * 8 + lg * 2;                                     \
        Pb[lm * 512 + ( wp      ^ (lm << 2))] = cvtpk(sval[0], sval[1]);        \
        Pb[lm * 512 + ((wp + 1) ^ (lm << 2))] = cvtpk(sval[2], sval[3]);        \
    }                                                                           \
} while (0)

    LOADZ(0, zA);
    #pragma unroll
    for (int pp = 0; pp < 8; ++pp) {
        PHASE(2 * pp,     zA, zB);
        PHASE(2 * pp + 1, zB, zA);
    }
    __syncthreads();

    // ---- softmax per head, in place on bf16 Pb ----
    {
        const int h = t >> 5, e = t & 31, hx = h << 2;
        unsigned int* Ph = &Pb[h * 512];
        float m = -1e30f;
        #pragma unroll
        for (int j = 0; j < 16; ++j) {
            unsigned int v = Ph[(e + j * 32) ^ hx];
            m = fmaxf(m, fmaxf(bflo(v), bfhi(v)));
        }
        #pragma unroll
        for (int d = 16; d >= 1; d >>= 1) m = fmaxf(m, __shfl_xor(m, d));
        float lsum = 0.f;
        #pragma unroll
        for (int j = 0; j < 16; ++j) {
            int idx = (e + j * 32) ^ hx;
            unsigned int v = Ph[idx];
            float p0 = __expf(bflo(v) - m);
            float p1 = __expf(bfhi(v) - m);
            lsum += p0 + p1;
            Ph[idx] = pk2(p0, p1);
        }
        #pragma unroll
        for (int d = 16; d >= 1; d >>= 1) lsum += __shfl_xor(lsum, d);
        if (e == 0) inv_l[h] = 1.f / lsum;
    }
    __syncthreads();

    // ---- PV via MFMA: C[comp][head] = Vt(96x1024) . P^T(1024x16) ----
    {
        const unsigned short* vtb = (const unsigned short*)((const char*)ws + VTB_BYTE);
        const char* PbB = (const char*)Pb;
        const int hh = lm & 7;
        const int nmt = (w < 2) ? 2 : 1;
        for (int ii = 0; ii < nmt; ++ii) {
            int mt = w + ii * 4;
            f32x4 acc = {0.f, 0.f, 0.f, 0.f};
            #pragma unroll 8
            for (int ks = 0; ks < 32; ++ks) {
                bf16x8 a = *(const bf16x8*)(vtb + (size_t)(mt * 16 + lm) * 1024 + ks * 32 + lg * 8);
                bf16x8 b = *(const bf16x8*)(PbB + hh * 2048 + ((ks * 64 + lg * 16) ^ (hh << 4)));
                acc = __builtin_amdgcn_mfma_f32_16x16x32_bf16(a, b, acc, 0, 0, 0);
            }
            if (lm < 8) {
                float il = inv_l[lm];
                #pragma unroll
                for (int r = 0; r < 4; ++r)
                    o_sh[lm * 96 + mt * 16 + lg * 4 + r] = acc[r] * il;
            }
        }
    }
    __syncthreads();

    // ---- output projections ----
    {
        int o2 = t >> 4, b = t & 15, g = GRADE_C[b];
        float acc = 0.f;
        #pragma unroll
        for (int i = 0; i < 32; ++i)
            acc += o_sh[(i >> 2) * 96 + (i & 3) * 16 + b] *
                   out_w_mv[(o2 * 32 + i) * 5 + g];
        d_out[(q * 16 + o2) * 16 + b] = acc;
    }
    if (t < 128) {
        const float* wv2 = out_w_s + t * 256;
        float acc = 0.f;
        #pragma unroll 4
        for (int c = 0; c < 256; ++c)
            acc += o_sh[(c >> 5) * 96 + 64 + (c & 31)] * wv2[c];
        d_out[262144 + q * 128 + t] = acc;
    }
#undef PHASE
#undef LOADZ
}

// ---------------- launch ----------------
extern "C" void kernel_launch(void* const* d_in, const int* in_sizes, int n_in,
                              void* d_out, int out_size, void* d_ws, size_t ws_size,
                              hipStream_t stream) {
    (void)in_sizes; (void)n_in; (void)out_size; (void)ws_size;
    const float* mv       = (const float*)d_in[0];
    const float* s        = (const float*)d_in[1];
    const float* z        = (const float*)d_in[2];
    const float* q_w_mv   = (const float*)d_in[3];
    const float* q_w_s    = (const float*)d_in[4];
    const float* k_w_mv   = (const float*)d_in[5];
    const float* k_w_s    = (const float*)d_in[6];
    const float* v_w_mv   = (const float*)d_in[7];
    const float* v_w_s    = (const float*)d_in[8];
    const float* out_w_mv = (const float*)d_in[9];
    const float* out_w_s  = (const float*)d_in[10];
    const float* ln_g     = (const float*)d_in[11];
    const float* ln_b     = (const float*)d_in[12];
    const float* bias_w   = (const float*)d_in[13];
    float* ws  = (float*)d_ws;
    float* out = (float*)d_out;

    kproj<<<1024, 256, 0, stream>>>(mv, s, q_w_mv, q_w_s, k_w_mv, k_w_s,
                                    v_w_mv, v_w_s, ln_g, ln_b, bias_w, ws);
    kfused<<<1024, 256, 0, stream>>>(z, ws, out_w_mv, out_w_s, out);
}